// Round 4
// baseline (714.759 us; speedup 1.0000x reference)
//
#include <hip/hip_runtime.h>

typedef __bf16 bf16;
typedef __bf16 bf16x8 __attribute__((ext_vector_type(8)));
typedef float  f32x4  __attribute__((ext_vector_type(4)));

#define DIM   1024
#define NH    16
#define NKV   4
#define HD    64
#define SLEN  264
#define BTOT  64            // B*T
#define MROWS (BTOT * SLEN) // 16896
#define NQKV  1536          // 1024 q + 256 k + 256 v
#define NZ    256
#define VPAD  288           // padded key dim of vt

// ---------------- async global->LDS (wave-uniform base + lane*16) ----------------
__device__ __forceinline__ void gl_lds16(const bf16* g, bf16* l) {
    __builtin_amdgcn_global_load_lds((__attribute__((address_space(1))) void*)(g),
                                     (__attribute__((address_space(3))) void*)(l),
                                     16, 0, 0);
}

// ---------------- f32 -> bf16 converters ----------------
__global__ void cvt_f32_bf16(const float* __restrict__ src, bf16* __restrict__ dst, int n) {
    int i = (blockIdx.x * 256 + threadIdx.x) * 4;
    if (i < n) {
        float4 v = *(const float4*)(src + i);
        dst[i + 0] = (bf16)v.x; dst[i + 1] = (bf16)v.y;
        dst[i + 2] = (bf16)v.z; dst[i + 3] = (bf16)v.w;
    }
}

__global__ void cvt_wcat(const float* __restrict__ wq, const float* __restrict__ wk,
                         const float* __restrict__ wv, bf16* __restrict__ dst) {
    int i = (blockIdx.x * 256 + threadIdx.x) * 4;   // total 1536*1024
    const float* src; int off;
    if (i < 1024 * 1024)      { src = wq; off = i; }
    else if (i < 1280 * 1024) { src = wk; off = i - 1024 * 1024; }
    else                      { src = wv; off = i - 1280 * 1024; }
    float4 v = *(const float4*)(src + off);
    dst[i + 0] = (bf16)v.x; dst[i + 1] = (bf16)v.y;
    dst[i + 2] = (bf16)v.z; dst[i + 3] = (bf16)v.w;
}

// ---------------- RoPE cos/sin table: ctab[s][d] for d in 0..31 (period-32 in head dim) ----------------
__global__ void rope_tab_kernel(float2* __restrict__ ctab) {
    int i = blockIdx.x * 256 + threadIdx.x;   // 8192 = 256 x 32
    int s = i >> 5, d = i & 31;
    const float LN1 = 0.5756462732485115f;    // ln(10000)/16
    float pos = (d < 16) ? (float)(s >> 4) : (float)(s & 15);
    float ang = pos * expf(-(float)(d & 15) * LN1);
    float sn, cs; sincosf(ang, &sn, &cs);
    ctab[i] = make_float2(cs, sn);
}

// ---------------- QKV GEMM with fused QKNorm + partial 2D-RoPE epilogue ----------------
// C[M,1536] = A[M,1024] @ W[1536,1024]^T. Each wave's 64 cols == one head.
// Grid: blockIdx.x = bn (fastest -> B stays L2-resident), blockIdx.y = bm.
// launch_bounds(256,6): VGPR<=85 -> 6 blocks/CU -> tail 48/1584 instead of 304/1584.
__global__ __launch_bounds__(256, 6) void gemm_qkv(const bf16* __restrict__ A,
                                                   const bf16* __restrict__ Bw,
                                                   bf16* __restrict__ out,
                                                   const float* __restrict__ qw,
                                                   const float* __restrict__ kw,
                                                   const float2* __restrict__ ctab) {
    __shared__ __align__(16) bf16 As[128 * 32];
    __shared__ __align__(16) bf16 Bs[128 * 32];
    const int tid  = threadIdx.x;
    const int wid  = tid >> 6, lane = tid & 63;
    const int quad = lane >> 4, r16 = lane & 15;
    const int bn = blockIdx.x, bm = blockIdx.y;
    const int wm = wid & 1, wn = wid >> 1;

    const bf16* Ag = A  + (size_t)(bm * 128 + (tid >> 2)) * DIM + (tid & 3) * 8;
    const bf16* Bg = Bw + (size_t)(bn * 128 + (tid >> 2)) * DIM + (tid & 3) * 8;
    bf16* AsW = As + wid * 512;
    bf16* BsW = Bs + wid * 512;

    f32x4 acc[4][4];
#pragma unroll
    for (int i = 0; i < 4; i++)
#pragma unroll
        for (int j = 0; j < 4; j++) acc[i][j] = (f32x4){0.f, 0.f, 0.f, 0.f};

    for (int k0 = 0; k0 < DIM; k0 += 32) {
        __syncthreads();
        gl_lds16(Ag + k0,             AsW);
        gl_lds16(Ag + 64 * DIM + k0,  AsW + 2048);
        gl_lds16(Bg + k0,             BsW);
        gl_lds16(Bg + 64 * DIM + k0,  BsW + 2048);
        __syncthreads();

        bf16x8 a[4], b[4];
#pragma unroll
        for (int i = 0; i < 4; i++) {
            a[i] = *(const bf16x8*)&As[(wm * 64 + i * 16 + r16) * 32 + quad * 8];
            b[i] = *(const bf16x8*)&Bs[(wn * 64 + i * 16 + r16) * 32 + quad * 8];
        }
#pragma unroll
        for (int i = 0; i < 4; i++)
#pragma unroll
            for (int j = 0; j < 4; j++)
                acc[i][j] = __builtin_amdgcn_mfma_f32_16x16x32_bf16(a[i], b[j], acc[i][j], 0, 0, 0);
    }

    const int colbase = bn * 128 + wn * 64;          // 64-aligned -> one head per wave
    const int rowbase = bm * 128 + wm * 64;
    if (bn < 10) {
        const float* w = (bn < 8) ? qw : kw;
        float wreg[4];
#pragma unroll
        for (int j = 0; j < 4; j++) wreg[j] = w[j * 16 + r16];
#pragma unroll
        for (int i = 0; i < 4; i++)
#pragma unroll
            for (int r = 0; r < 4; r++) {
                float ss = 0.f;
#pragma unroll
                for (int j = 0; j < 4; j++) ss += acc[i][j][r] * acc[i][j][r];
                ss += __shfl_xor(ss, 1, 64);
                ss += __shfl_xor(ss, 2, 64);
                ss += __shfl_xor(ss, 4, 64);
                ss += __shfl_xor(ss, 8, 64);
                float rms = rsqrtf(ss * (1.f / 64.f) + 1e-6f);
                float xv[4];
#pragma unroll
                for (int j = 0; j < 4; j++) xv[j] = acc[i][j][r] * rms * wreg[j];
                int gm = rowbase + i * 16 + quad * 4 + r;
                int s = gm % SLEN;
                if (s < NZ) {   // partial 2D RoPE; pairs (j, j+2) are lane-local
                    float2 cs0 = ctab[s * 32 + r16];
                    float2 cs1 = ctab[s * 32 + 16 + r16];
                    float a0 = xv[0] * cs0.x - xv[2] * cs0.y;
                    float a2 = xv[2] * cs0.x + xv[0] * cs0.y;
                    float a1 = xv[1] * cs1.x - xv[3] * cs1.y;
                    float a3 = xv[3] * cs1.x + xv[1] * cs1.y;
                    xv[0] = a0; xv[1] = a1; xv[2] = a2; xv[3] = a3;
                }
                size_t rowoff = (size_t)gm * NQKV + colbase + r16;
#pragma unroll
                for (int j = 0; j < 4; j++) out[rowoff + j * 16] = (bf16)xv[j];
            }
    } else {
#pragma unroll
        for (int i = 0; i < 4; i++)
#pragma unroll
            for (int j = 0; j < 4; j++)
#pragma unroll
                for (int r = 0; r < 4; r++) {
                    int gm = rowbase + i * 16 + quad * 4 + r;
                    int gn = colbase + j * 16 + r16;
                    out[(size_t)gm * NQKV + gn] = (bf16)acc[i][j][r];
                }
    }
}

// ---------------- plain m97-pattern GEMM (O-projection): C[M,N]=A@B^T, f32 out ----------------
// Grid: blockIdx.x = bn (fastest), blockIdx.y = bm -> B (2 MB) L2-resident.
__global__ __launch_bounds__(256) void gemm_bt(const bf16* __restrict__ A,
                                               const bf16* __restrict__ Bw,
                                               float* __restrict__ Cout,
                                               int Nld, int K) {
    __shared__ __align__(16) bf16 As[128 * 32];
    __shared__ __align__(16) bf16 Bs[128 * 32];
    const int tid  = threadIdx.x;
    const int wid  = tid >> 6, lane = tid & 63;
    const int quad = lane >> 4, r16 = lane & 15;
    const int bn = blockIdx.x, bm = blockIdx.y;
    const int wm = wid & 1, wn = wid >> 1;

    const bf16* Ag = A  + (size_t)(bm * 128 + (tid >> 2)) * K + (tid & 3) * 8;
    const bf16* Bg = Bw + (size_t)(bn * 128 + (tid >> 2)) * K + (tid & 3) * 8;
    bf16* AsW = As + wid * 512;
    bf16* BsW = Bs + wid * 512;

    f32x4 acc[4][4];
#pragma unroll
    for (int i = 0; i < 4; i++)
#pragma unroll
        for (int j = 0; j < 4; j++) acc[i][j] = (f32x4){0.f, 0.f, 0.f, 0.f};

    for (int k0 = 0; k0 < K; k0 += 32) {
        __syncthreads();
        gl_lds16(Ag + k0,           AsW);
        gl_lds16(Ag + 64 * K + k0,  AsW + 2048);
        gl_lds16(Bg + k0,           BsW);
        gl_lds16(Bg + 64 * K + k0,  BsW + 2048);
        __syncthreads();

        bf16x8 a[4], b[4];
#pragma unroll
        for (int i = 0; i < 4; i++) {
            a[i] = *(const bf16x8*)&As[(wm * 64 + i * 16 + r16) * 32 + quad * 8];
            b[i] = *(const bf16x8*)&Bs[(wn * 64 + i * 16 + r16) * 32 + quad * 8];
        }
#pragma unroll
        for (int i = 0; i < 4; i++)
#pragma unroll
            for (int j = 0; j < 4; j++)
                acc[i][j] = __builtin_amdgcn_mfma_f32_16x16x32_bf16(a[i], b[j], acc[i][j], 0, 0, 0);
    }

#pragma unroll
    for (int i = 0; i < 4; i++)
#pragma unroll
        for (int j = 0; j < 4; j++)
#pragma unroll
            for (int r = 0; r < 4; r++) {
                int gm = bm * 128 + wm * 64 + i * 16 + quad * 4 + r;
                int gn = bn * 128 + wn * 64 + j * 16 + r16;
                Cout[(size_t)gm * Nld + gn] = acc[i][j][r];
            }
}

// ---------------- V transpose: qkv V region -> vt[(bt,kv)][d][key], zero-padded to 288 keys ----------------
__global__ __launch_bounds__(256) void vtrans_kernel(const bf16* __restrict__ qkv,
                                                     bf16* __restrict__ vt) {
    __shared__ bf16 Ls[64 * 272];
    const int tid = threadIdx.x;
    const int b = blockIdx.x, bt = b >> 2, kv = b & 3;
    const int part = tid >> 5;      // 0..7 (dim octet)
    const int rr   = tid & 31;      // row within pass
#pragma unroll
    for (int pass = 0; pass < 9; ++pass) {
        int row = pass * 32 + rr;
        if (row < SLEN) {
            bf16x8 v = *(const bf16x8*)(qkv + (size_t)(bt * SLEN + row) * NQKV + 1280 + kv * 64 + part * 8);
#pragma unroll
            for (int j = 0; j < 8; j++) Ls[(part * 8 + j) * 272 + row] = v[j];
        }
    }
    __syncthreads();
    const int d = tid >> 2, seg = tid & 3;
    size_t obase = ((size_t)b * 64 + d) * VPAD;
#pragma unroll
    for (int m = 0; m < 9; ++m) {
        int col = seg * 72 + m * 8;
        bf16x8 o;
#pragma unroll
        for (int j = 0; j < 8; j++) {
            int s = col + j;
            o[j] = (s < SLEN) ? Ls[d * 272 + s] : (bf16)0.f;
        }
        *(bf16x8*)(vt + obase + col) = o;
    }
}

// ---------------- attention v4: one wave per (32-row qtile-pair, head, bt) ----------------
// K prefetched one chunk ahead; softcap via odd-poly tanh (|z|<=0.16) + single exp2.
__global__ __launch_bounds__(256) void attn_kernel(const bf16* __restrict__ qkv,
                                                   const bf16* __restrict__ vt,
                                                   bf16* __restrict__ aout) {
    const int PLD = 40;
    __shared__ __align__(16) bf16 Pb[4][2][16 * PLD];   // per-wave, per-qtile P buffers

    const int tid = threadIdx.x;
    const int wid = tid >> 6, lane = tid & 63;
    const int quad = lane >> 4, r16 = lane & 15;
    const int qp = blockIdx.x;           // 0..8 (9 pairs of 16-row tiles = 288 rows)
    const int kv = blockIdx.y, bt = blockIdx.z;
    const int h = kv * 4 + wid;

    // Q A-fragments for two 16-row tiles
    bf16x8 qa[2][2];
#pragma unroll
    for (int qi = 0; qi < 2; qi++) {
        int q0 = qp * 32 + qi * 16 + r16;
        int qcl = q0 < SLEN ? q0 : SLEN - 1;
        const bf16* qb = qkv + (size_t)(bt * SLEN + qcl) * NQKV + h * HD + quad * 8;
        qa[qi][0] = *(const bf16x8*)qb;
        qa[qi][1] = *(const bf16x8*)(qb + 32);
    }

    f32x4 oacc[2][4];
    float lsum[2][4];
#pragma unroll
    for (int qi = 0; qi < 2; qi++)
#pragma unroll
        for (int i = 0; i < 4; i++) { oacc[qi][i] = (f32x4){0.f, 0.f, 0.f, 0.f}; lsum[qi][i] = 0.f; }

    const bf16* kbase = qkv + (size_t)bt * SLEN * NQKV + 1024 + kv * HD + quad * 8;
    const bf16* vbase = vt + (size_t)(bt * 4 + kv) * HD * VPAD;

    bf16x8 nk[2][2];
#pragma unroll
    for (int kt = 0; kt < 2; kt++) {
        int key = kt * 16 + r16;
        const bf16* kp = kbase + (size_t)key * NQKV;
        nk[kt][0] = *(const bf16x8*)kp;
        nk[kt][1] = *(const bf16x8*)(kp + 32);
    }

    for (int c = 0; c < 9; ++c) {
        bf16x8 ck[2][2];
#pragma unroll
        for (int kt = 0; kt < 2; kt++) { ck[kt][0] = nk[kt][0]; ck[kt][1] = nk[kt][1]; }
        if (c < 8) {   // prefetch next chunk's K
#pragma unroll
            for (int kt = 0; kt < 2; kt++) {
                int key = (c + 1) * 32 + kt * 16 + r16;
                int kc = key < SLEN ? key : SLEN - 1;
                const bf16* kp = kbase + (size_t)kc * NQKV;
                nk[kt][0] = *(const bf16x8*)kp;
                nk[kt][1] = *(const bf16x8*)(kp + 32);
            }
        }
        // V B-fragments (coalesced from vt; covered by QK+softcap latency)
        bf16x8 cv[4];
#pragma unroll
        for (int dt = 0; dt < 4; ++dt)
            cv[dt] = *(const bf16x8*)(vbase + (size_t)(dt * 16 + r16) * VPAD + c * 32 + quad * 8);

        // QK^T
        f32x4 s[2][2];
#pragma unroll
        for (int qi = 0; qi < 2; qi++)
#pragma unroll
            for (int kt = 0; kt < 2; kt++) {
                f32x4 t = (f32x4){0.f, 0.f, 0.f, 0.f};
                t = __builtin_amdgcn_mfma_f32_16x16x32_bf16(qa[qi][0], ck[kt][0], t, 0, 0, 0);
                t = __builtin_amdgcn_mfma_f32_16x16x32_bf16(qa[qi][1], ck[kt][1], t, 0, 0, 0);
                s[qi][kt] = t;
            }

        // softcap: p = exp(50*tanh(sc/400))  [|z|<=0.16 -> 5th-order odd poly, err<2e-7]
#pragma unroll
        for (int qi = 0; qi < 2; qi++) {
            bf16* Pw = &Pb[wid][qi][0];
#pragma unroll
            for (int kt = 0; kt < 2; kt++)
#pragma unroll
                for (int r = 0; r < 4; ++r) {
                    int key = c * 32 + kt * 16 + r16;
                    float sc = s[qi][kt][r];
                    float z = sc * 0.0025f;                       // sc*SCALE/50
                    float z2 = z * z;
                    float poly = fmaf(z2, fmaf(z2, 0.133333333f, -0.333333333f), 1.f);
                    float p = exp2f(sc * 0.18033688f * poly);     // 50*log2e*z*poly
                    p = (key < SLEN) ? p : 0.f;
                    bf16 pb = (bf16)p;
                    lsum[qi][r] += (float)pb;
                    Pw[(quad * 4 + r) * PLD + kt * 16 + r16] = pb;
                }
            // C-layout -> A-layout repack through per-wave LDS (wave-coherent, no barrier)
            bf16x8 pa = *(const bf16x8*)&Pw[r16 * PLD + quad * 8];
#pragma unroll
            for (int dt = 0; dt < 4; ++dt)
                oacc[qi][dt] = __builtin_amdgcn_mfma_f32_16x16x32_bf16(pa, cv[dt], oacc[qi][dt], 0, 0, 0);
        }
    }

    // finalize: reduce l across the 16 key-lanes, divide, store
#pragma unroll
    for (int qi = 0; qi < 2; qi++)
#pragma unroll
        for (int r = 0; r < 4; ++r) {
            float l = lsum[qi][r];
            l += __shfl_xor(l, 1, 64);
            l += __shfl_xor(l, 2, 64);
            l += __shfl_xor(l, 4, 64);
            l += __shfl_xor(l, 8, 64);
            float inv = 1.f / l;
            int q = qp * 32 + qi * 16 + quad * 4 + r;
            if (q < SLEN) {
                size_t base = (size_t)(bt * SLEN + q) * (NH * HD) + h * HD;
#pragma unroll
                for (int dt = 0; dt < 4; ++dt)
                    aout[base + dt * 16 + r16] = (bf16)(oacc[qi][dt][r] * inv);
            }
        }
}

// ---------------- launcher ----------------
extern "C" void kernel_launch(void* const* d_in, const int* in_sizes, int n_in,
                              void* d_out, int out_size, void* d_ws, size_t ws_size,
                              hipStream_t stream) {
    const float* x   = (const float*)d_in[0];
    const float* wq  = (const float*)d_in[1];
    const float* wk  = (const float*)d_in[2];
    const float* wv  = (const float*)d_in[3];
    const float* wo  = (const float*)d_in[4];
    const float* qnw = (const float*)d_in[5];
    const float* knw = (const float*)d_in[6];

    bf16* xbf  = (bf16*)d_ws;                        // 16896x1024 (reused as aout)
    bf16* wcat = xbf  + (size_t)MROWS * DIM;         // 1536x1024  [wq;wk;wv]
    bf16* wobf = wcat + (size_t)NQKV * DIM;          // 1024x1024
    bf16* qkv  = wobf + (size_t)DIM * DIM;           // 16896x1536
    bf16* vt   = qkv  + (size_t)MROWS * NQKV;        // 256x64x288
    float2* ctab = (float2*)(vt + (size_t)BTOT * NKV * HD * VPAD);  // 256x32
    bf16* aout = xbf;                                // xbf dead after gemm_qkv

    rope_tab_kernel<<<32, 256, 0, stream>>>(ctab);
    cvt_f32_bf16<<<(MROWS * DIM) / 1024, 256, 0, stream>>>(x, xbf, MROWS * DIM);
    cvt_wcat<<<(NQKV * DIM) / 1024, 256, 0, stream>>>(wq, wk, wv, wcat);
    cvt_f32_bf16<<<(DIM * DIM) / 1024, 256, 0, stream>>>(wo, wobf, DIM * DIM);

    gemm_qkv<<<dim3(NQKV / 128, MROWS / 128), 256, 0, stream>>>(xbf, wcat, qkv, qnw, knw, ctab);
    vtrans_kernel<<<BTOT * NKV, 256, 0, stream>>>(qkv, vt);
    attn_kernel<<<dim3(9, NKV, BTOT), 256, 0, stream>>>(qkv, vt, aout);
    gemm_bt<<<dim3(DIM / 128, MROWS / 128), 256, 0, stream>>>(aout, wobf, (float*)d_out, DIM, DIM);
}

// Round 5
// 385.900 us; speedup vs baseline: 1.8522x; 1.8522x over previous
//
#include <hip/hip_runtime.h>

typedef __bf16 bf16;
typedef __bf16 bf16x8 __attribute__((ext_vector_type(8)));
typedef float  f32x4  __attribute__((ext_vector_type(4)));

#define DIM   1024
#define NH    16
#define NKV   4
#define HD    64
#define SLEN  264
#define BTOT  64            // B*T
#define MROWS (BTOT * SLEN) // 16896
#define NQKV  1536          // 1024 q + 256 k + 256 v
#define NZ    256
#define VPAD  288           // padded key dim of vt

// ---------------- async global->LDS (wave-uniform base + lane*16) ----------------
__device__ __forceinline__ void gl_lds16(const bf16* g, bf16* l) {
    __builtin_amdgcn_global_load_lds((__attribute__((address_space(1))) void*)(g),
                                     (__attribute__((address_space(3))) void*)(l),
                                     16, 0, 0);
}

// ---------------- f32 -> bf16 converters ----------------
__global__ void cvt_f32_bf16(const float* __restrict__ src, bf16* __restrict__ dst, int n) {
    int i = (blockIdx.x * 256 + threadIdx.x) * 4;
    if (i < n) {
        float4 v = *(const float4*)(src + i);
        dst[i + 0] = (bf16)v.x; dst[i + 1] = (bf16)v.y;
        dst[i + 2] = (bf16)v.z; dst[i + 3] = (bf16)v.w;
    }
}

__global__ void cvt_wcat(const float* __restrict__ wq, const float* __restrict__ wk,
                         const float* __restrict__ wv, bf16* __restrict__ dst) {
    int i = (blockIdx.x * 256 + threadIdx.x) * 4;   // total 1536*1024
    const float* src; int off;
    if (i < 1024 * 1024)      { src = wq; off = i; }
    else if (i < 1280 * 1024) { src = wk; off = i - 1024 * 1024; }
    else                      { src = wv; off = i - 1280 * 1024; }
    float4 v = *(const float4*)(src + off);
    dst[i + 0] = (bf16)v.x; dst[i + 1] = (bf16)v.y;
    dst[i + 2] = (bf16)v.z; dst[i + 3] = (bf16)v.w;
}

// ---------------- RoPE cos/sin table: ctab[s][d] for d in 0..31 (period-32 in head dim) ----------------
__global__ void rope_tab_kernel(float2* __restrict__ ctab) {
    int i = blockIdx.x * 256 + threadIdx.x;   // 8192 = 256 x 32
    int s = i >> 5, d = i & 31;
    const float LN1 = 0.5756462732485115f;    // ln(10000)/16
    float pos = (d < 16) ? (float)(s >> 4) : (float)(s & 15);
    float ang = pos * expf(-(float)(d & 15) * LN1);
    float sn, cs; sincosf(ang, &sn, &cs);
    ctab[i] = make_float2(cs, sn);
}

// ---------------- QKV GEMM with fused QKNorm + partial 2D-RoPE epilogue ----------------
// C[M,1536] = A[M,1024] @ W[1536,1024]^T. Each wave's 64 cols == one head.
// Grid: blockIdx.x = bn (fastest -> B stays L2-resident), blockIdx.y = bm.
// NOTE: no min-waves launch_bounds — (256,6) capped VGPR at 40 and spilled the
// 64-VGPR accumulator to scratch (1 GB of spill traffic, 4x regression, R4).
__global__ __launch_bounds__(256) void gemm_qkv(const bf16* __restrict__ A,
                                                const bf16* __restrict__ Bw,
                                                bf16* __restrict__ out,
                                                const float* __restrict__ qw,
                                                const float* __restrict__ kw,
                                                const float2* __restrict__ ctab) {
    __shared__ __align__(16) bf16 As[128 * 32];
    __shared__ __align__(16) bf16 Bs[128 * 32];
    const int tid  = threadIdx.x;
    const int wid  = tid >> 6, lane = tid & 63;
    const int quad = lane >> 4, r16 = lane & 15;
    const int bn = blockIdx.x, bm = blockIdx.y;
    const int wm = wid & 1, wn = wid >> 1;

    const bf16* Ag = A  + (size_t)(bm * 128 + (tid >> 2)) * DIM + (tid & 3) * 8;
    const bf16* Bg = Bw + (size_t)(bn * 128 + (tid >> 2)) * DIM + (tid & 3) * 8;
    bf16* AsW = As + wid * 512;
    bf16* BsW = Bs + wid * 512;

    f32x4 acc[4][4];
#pragma unroll
    for (int i = 0; i < 4; i++)
#pragma unroll
        for (int j = 0; j < 4; j++) acc[i][j] = (f32x4){0.f, 0.f, 0.f, 0.f};

    for (int k0 = 0; k0 < DIM; k0 += 32) {
        __syncthreads();
        gl_lds16(Ag + k0,             AsW);
        gl_lds16(Ag + 64 * DIM + k0,  AsW + 2048);
        gl_lds16(Bg + k0,             BsW);
        gl_lds16(Bg + 64 * DIM + k0,  BsW + 2048);
        __syncthreads();

        bf16x8 a[4], b[4];
#pragma unroll
        for (int i = 0; i < 4; i++) {
            a[i] = *(const bf16x8*)&As[(wm * 64 + i * 16 + r16) * 32 + quad * 8];
            b[i] = *(const bf16x8*)&Bs[(wn * 64 + i * 16 + r16) * 32 + quad * 8];
        }
#pragma unroll
        for (int i = 0; i < 4; i++)
#pragma unroll
            for (int j = 0; j < 4; j++)
                acc[i][j] = __builtin_amdgcn_mfma_f32_16x16x32_bf16(a[i], b[j], acc[i][j], 0, 0, 0);
    }

    const int colbase = bn * 128 + wn * 64;          // 64-aligned -> one head per wave
    const int rowbase = bm * 128 + wm * 64;
    if (bn < 10) {
        const float* w = (bn < 8) ? qw : kw;
        float wreg[4];
#pragma unroll
        for (int j = 0; j < 4; j++) wreg[j] = w[j * 16 + r16];
#pragma unroll
        for (int i = 0; i < 4; i++)
#pragma unroll
            for (int r = 0; r < 4; r++) {
                float ss = 0.f;
#pragma unroll
                for (int j = 0; j < 4; j++) ss += acc[i][j][r] * acc[i][j][r];
                ss += __shfl_xor(ss, 1, 64);
                ss += __shfl_xor(ss, 2, 64);
                ss += __shfl_xor(ss, 4, 64);
                ss += __shfl_xor(ss, 8, 64);
                float rms = rsqrtf(ss * (1.f / 64.f) + 1e-6f);
                float xv[4];
#pragma unroll
                for (int j = 0; j < 4; j++) xv[j] = acc[i][j][r] * rms * wreg[j];
                int gm = rowbase + i * 16 + quad * 4 + r;
                int s = gm % SLEN;
                if (s < NZ) {   // partial 2D RoPE; pairs (j, j+2) are lane-local
                    float2 cs0 = ctab[s * 32 + r16];
                    float2 cs1 = ctab[s * 32 + 16 + r16];
                    float a0 = xv[0] * cs0.x - xv[2] * cs0.y;
                    float a2 = xv[2] * cs0.x + xv[0] * cs0.y;
                    float a1 = xv[1] * cs1.x - xv[3] * cs1.y;
                    float a3 = xv[3] * cs1.x + xv[1] * cs1.y;
                    xv[0] = a0; xv[1] = a1; xv[2] = a2; xv[3] = a3;
                }
                size_t rowoff = (size_t)gm * NQKV + colbase + r16;
#pragma unroll
                for (int j = 0; j < 4; j++) out[rowoff + j * 16] = (bf16)xv[j];
            }
    } else {
#pragma unroll
        for (int i = 0; i < 4; i++)
#pragma unroll
            for (int j = 0; j < 4; j++)
#pragma unroll
                for (int r = 0; r < 4; r++) {
                    int gm = rowbase + i * 16 + quad * 4 + r;
                    int gn = colbase + j * 16 + r16;
                    out[(size_t)gm * NQKV + gn] = (bf16)acc[i][j][r];
                }
    }
}

// ---------------- plain m97-pattern GEMM (O-projection): C[M,N]=A@B^T, f32 out ----------------
// Grid: blockIdx.x = bn (fastest), blockIdx.y = bm -> B (2 MB) L2-resident.
__global__ __launch_bounds__(256) void gemm_bt(const bf16* __restrict__ A,
                                               const bf16* __restrict__ Bw,
                                               float* __restrict__ Cout,
                                               int Nld, int K) {
    __shared__ __align__(16) bf16 As[128 * 32];
    __shared__ __align__(16) bf16 Bs[128 * 32];
    const int tid  = threadIdx.x;
    const int wid  = tid >> 6, lane = tid & 63;
    const int quad = lane >> 4, r16 = lane & 15;
    const int bn = blockIdx.x, bm = blockIdx.y;
    const int wm = wid & 1, wn = wid >> 1;

    const bf16* Ag = A  + (size_t)(bm * 128 + (tid >> 2)) * K + (tid & 3) * 8;
    const bf16* Bg = Bw + (size_t)(bn * 128 + (tid >> 2)) * K + (tid & 3) * 8;
    bf16* AsW = As + wid * 512;
    bf16* BsW = Bs + wid * 512;

    f32x4 acc[4][4];
#pragma unroll
    for (int i = 0; i < 4; i++)
#pragma unroll
        for (int j = 0; j < 4; j++) acc[i][j] = (f32x4){0.f, 0.f, 0.f, 0.f};

    for (int k0 = 0; k0 < K; k0 += 32) {
        __syncthreads();
        gl_lds16(Ag + k0,           AsW);
        gl_lds16(Ag + 64 * K + k0,  AsW + 2048);
        gl_lds16(Bg + k0,           BsW);
        gl_lds16(Bg + 64 * K + k0,  BsW + 2048);
        __syncthreads();

        bf16x8 a[4], b[4];
#pragma unroll
        for (int i = 0; i < 4; i++) {
            a[i] = *(const bf16x8*)&As[(wm * 64 + i * 16 + r16) * 32 + quad * 8];
            b[i] = *(const bf16x8*)&Bs[(wn * 64 + i * 16 + r16) * 32 + quad * 8];
        }
#pragma unroll
        for (int i = 0; i < 4; i++)
#pragma unroll
            for (int j = 0; j < 4; j++)
                acc[i][j] = __builtin_amdgcn_mfma_f32_16x16x32_bf16(a[i], b[j], acc[i][j], 0, 0, 0);
    }

#pragma unroll
    for (int i = 0; i < 4; i++)
#pragma unroll
        for (int j = 0; j < 4; j++)
#pragma unroll
            for (int r = 0; r < 4; r++) {
                int gm = bm * 128 + wm * 64 + i * 16 + quad * 4 + r;
                int gn = bn * 128 + wn * 64 + j * 16 + r16;
                Cout[(size_t)gm * Nld + gn] = acc[i][j][r];
            }
}

// ---------------- V transpose: qkv V region -> vt[(bt,kv)][d][key], zero-padded to 288 keys ----------------
__global__ __launch_bounds__(256) void vtrans_kernel(const bf16* __restrict__ qkv,
                                                     bf16* __restrict__ vt) {
    __shared__ bf16 Ls[64 * 272];
    const int tid = threadIdx.x;
    const int b = blockIdx.x, bt = b >> 2, kv = b & 3;
    const int part = tid >> 5;      // 0..7 (dim octet)
    const int rr   = tid & 31;      // row within pass
#pragma unroll
    for (int pass = 0; pass < 9; ++pass) {
        int row = pass * 32 + rr;
        if (row < SLEN) {
            bf16x8 v = *(const bf16x8*)(qkv + (size_t)(bt * SLEN + row) * NQKV + 1280 + kv * 64 + part * 8);
#pragma unroll
            for (int j = 0; j < 8; j++) Ls[(part * 8 + j) * 272 + row] = v[j];
        }
    }
    __syncthreads();
    const int d = tid >> 2, seg = tid & 3;
    size_t obase = ((size_t)b * 64 + d) * VPAD;
#pragma unroll
    for (int m = 0; m < 9; ++m) {
        int col = seg * 72 + m * 8;
        bf16x8 o;
#pragma unroll
        for (int j = 0; j < 8; j++) {
            int s = col + j;
            o[j] = (s < SLEN) ? Ls[d * 272 + s] : (bf16)0.f;
        }
        *(bf16x8*)(vt + obase + col) = o;
    }
}

// ---------------- attention v4: one wave per (32-row qtile-pair, head, bt) ----------------
// K prefetched one chunk ahead; softcap via odd-poly tanh (|z|<=0.16) + single exp2.
__global__ __launch_bounds__(256) void attn_kernel(const bf16* __restrict__ qkv,
                                                   const bf16* __restrict__ vt,
                                                   bf16* __restrict__ aout) {
    const int PLD = 40;
    __shared__ __align__(16) bf16 Pb[4][2][16 * PLD];   // per-wave, per-qtile P buffers

    const int tid = threadIdx.x;
    const int wid = tid >> 6, lane = tid & 63;
    const int quad = lane >> 4, r16 = lane & 15;
    const int qp = blockIdx.x;           // 0..8 (9 pairs of 16-row tiles = 288 rows)
    const int kv = blockIdx.y, bt = blockIdx.z;
    const int h = kv * 4 + wid;

    // Q A-fragments for two 16-row tiles
    bf16x8 qa[2][2];
#pragma unroll
    for (int qi = 0; qi < 2; qi++) {
        int q0 = qp * 32 + qi * 16 + r16;
        int qcl = q0 < SLEN ? q0 : SLEN - 1;
        const bf16* qb = qkv + (size_t)(bt * SLEN + qcl) * NQKV + h * HD + quad * 8;
        qa[qi][0] = *(const bf16x8*)qb;
        qa[qi][1] = *(const bf16x8*)(qb + 32);
    }

    f32x4 oacc[2][4];
    float lsum[2][4];
#pragma unroll
    for (int qi = 0; qi < 2; qi++)
#pragma unroll
        for (int i = 0; i < 4; i++) { oacc[qi][i] = (f32x4){0.f, 0.f, 0.f, 0.f}; lsum[qi][i] = 0.f; }

    const bf16* kbase = qkv + (size_t)bt * SLEN * NQKV + 1024 + kv * HD + quad * 8;
    const bf16* vbase = vt + (size_t)(bt * 4 + kv) * HD * VPAD;

    bf16x8 nk[2][2];
#pragma unroll
    for (int kt = 0; kt < 2; kt++) {
        int key = kt * 16 + r16;
        const bf16* kp = kbase + (size_t)key * NQKV;
        nk[kt][0] = *(const bf16x8*)kp;
        nk[kt][1] = *(const bf16x8*)(kp + 32);
    }

    for (int c = 0; c < 9; ++c) {
        bf16x8 ck[2][2];
#pragma unroll
        for (int kt = 0; kt < 2; kt++) { ck[kt][0] = nk[kt][0]; ck[kt][1] = nk[kt][1]; }
        if (c < 8) {   // prefetch next chunk's K
#pragma unroll
            for (int kt = 0; kt < 2; kt++) {
                int key = (c + 1) * 32 + kt * 16 + r16;
                int kc = key < SLEN ? key : SLEN - 1;
                const bf16* kp = kbase + (size_t)kc * NQKV;
                nk[kt][0] = *(const bf16x8*)kp;
                nk[kt][1] = *(const bf16x8*)(kp + 32);
            }
        }
        // V B-fragments (coalesced from vt; covered by QK+softcap latency)
        bf16x8 cv[4];
#pragma unroll
        for (int dt = 0; dt < 4; ++dt)
            cv[dt] = *(const bf16x8*)(vbase + (size_t)(dt * 16 + r16) * VPAD + c * 32 + quad * 8);

        // QK^T
        f32x4 s[2][2];
#pragma unroll
        for (int qi = 0; qi < 2; qi++)
#pragma unroll
            for (int kt = 0; kt < 2; kt++) {
                f32x4 t = (f32x4){0.f, 0.f, 0.f, 0.f};
                t = __builtin_amdgcn_mfma_f32_16x16x32_bf16(qa[qi][0], ck[kt][0], t, 0, 0, 0);
                t = __builtin_amdgcn_mfma_f32_16x16x32_bf16(qa[qi][1], ck[kt][1], t, 0, 0, 0);
                s[qi][kt] = t;
            }

        // softcap: p = exp(50*tanh(sc/400))  [|z|<=0.16 -> 5th-order odd poly, err<2e-7]
#pragma unroll
        for (int qi = 0; qi < 2; qi++) {
            bf16* Pw = &Pb[wid][qi][0];
#pragma unroll
            for (int kt = 0; kt < 2; kt++)
#pragma unroll
                for (int r = 0; r < 4; ++r) {
                    int key = c * 32 + kt * 16 + r16;
                    float sc = s[qi][kt][r];
                    float z = sc * 0.0025f;                       // sc*SCALE/50
                    float z2 = z * z;
                    float poly = fmaf(z2, fmaf(z2, 0.133333333f, -0.333333333f), 1.f);
                    float p = exp2f(sc * 0.18033688f * poly);     // 50*log2e*z*poly
                    p = (key < SLEN) ? p : 0.f;
                    bf16 pb = (bf16)p;
                    lsum[qi][r] += (float)pb;
                    Pw[(quad * 4 + r) * PLD + kt * 16 + r16] = pb;
                }
            // C-layout -> A-layout repack through per-wave LDS (wave-coherent, no barrier)
            bf16x8 pa = *(const bf16x8*)&Pw[r16 * PLD + quad * 8];
#pragma unroll
            for (int dt = 0; dt < 4; ++dt)
                oacc[qi][dt] = __builtin_amdgcn_mfma_f32_16x16x32_bf16(pa, cv[dt], oacc[qi][dt], 0, 0, 0);
        }
    }

    // finalize: reduce l across the 16 key-lanes, divide, store
#pragma unroll
    for (int qi = 0; qi < 2; qi++)
#pragma unroll
        for (int r = 0; r < 4; ++r) {
            float l = lsum[qi][r];
            l += __shfl_xor(l, 1, 64);
            l += __shfl_xor(l, 2, 64);
            l += __shfl_xor(l, 4, 64);
            l += __shfl_xor(l, 8, 64);
            float inv = 1.f / l;
            int q = qp * 32 + qi * 16 + quad * 4 + r;
            if (q < SLEN) {
                size_t base = (size_t)(bt * SLEN + q) * (NH * HD) + h * HD;
#pragma unroll
                for (int dt = 0; dt < 4; ++dt)
                    aout[base + dt * 16 + r16] = (bf16)(oacc[qi][dt][r] * inv);
            }
        }
}

// ---------------- launcher ----------------
extern "C" void kernel_launch(void* const* d_in, const int* in_sizes, int n_in,
                              void* d_out, int out_size, void* d_ws, size_t ws_size,
                              hipStream_t stream) {
    const float* x   = (const float*)d_in[0];
    const float* wq  = (const float*)d_in[1];
    const float* wk  = (const float*)d_in[2];
    const float* wv  = (const float*)d_in[3];
    const float* wo  = (const float*)d_in[4];
    const float* qnw = (const float*)d_in[5];
    const float* knw = (const float*)d_in[6];

    bf16* xbf  = (bf16*)d_ws;                        // 16896x1024 (reused as aout)
    bf16* wcat = xbf  + (size_t)MROWS * DIM;         // 1536x1024  [wq;wk;wv]
    bf16* wobf = wcat + (size_t)NQKV * DIM;          // 1024x1024
    bf16* qkv  = wobf + (size_t)DIM * DIM;           // 16896x1536
    bf16* vt   = qkv  + (size_t)MROWS * NQKV;        // 256x64x288
    float2* ctab = (float2*)(vt + (size_t)BTOT * NKV * HD * VPAD);  // 256x32
    bf16* aout = xbf;                                // xbf dead after gemm_qkv

    rope_tab_kernel<<<32, 256, 0, stream>>>(ctab);
    cvt_f32_bf16<<<(MROWS * DIM) / 1024, 256, 0, stream>>>(x, xbf, MROWS * DIM);
    cvt_wcat<<<(NQKV * DIM) / 1024, 256, 0, stream>>>(wq, wk, wv, wcat);
    cvt_f32_bf16<<<(DIM * DIM) / 1024, 256, 0, stream>>>(wo, wobf, DIM * DIM);

    gemm_qkv<<<dim3(NQKV / 128, MROWS / 128), 256, 0, stream>>>(xbf, wcat, qkv, qnw, knw, ctab);
    vtrans_kernel<<<BTOT * NKV, 256, 0, stream>>>(qkv, vt);
    attn_kernel<<<dim3(9, NKV, BTOT), 256, 0, stream>>>(qkv, vt, aout);
    gemm_bt<<<dim3(DIM / 128, MROWS / 128), 256, 0, stream>>>(aout, wobf, (float*)d_out, DIM, DIM);
}

// Round 6
// 355.545 us; speedup vs baseline: 2.0103x; 1.0854x over previous
//
#include <hip/hip_runtime.h>

typedef __bf16 bf16;
typedef __bf16 bf16x8 __attribute__((ext_vector_type(8)));
typedef float  f32x4  __attribute__((ext_vector_type(4)));

#define DIM   1024
#define NH    16
#define NKV   4
#define HD    64
#define SLEN  264
#define BTOT  64            // B*T
#define MROWS (BTOT * SLEN) // 16896
#define NQKV  1536          // 1024 q + 256 k + 256 v
#define NZ    256
#define VPAD  288           // padded key dim of vt

// ---------------- async global->LDS (wave-uniform LDS base + lane*16; global src is per-lane) ----------------
__device__ __forceinline__ void gl_lds16(const bf16* g, bf16* l) {
    __builtin_amdgcn_global_load_lds((__attribute__((address_space(1))) void*)(g),
                                     (__attribute__((address_space(3))) void*)(l),
                                     16, 0, 0);
}

// ---------------- f32 -> bf16 converters ----------------
__global__ void cvt_f32_bf16(const float* __restrict__ src, bf16* __restrict__ dst, int n) {
    int i = (blockIdx.x * 256 + threadIdx.x) * 4;
    if (i < n) {
        float4 v = *(const float4*)(src + i);
        dst[i + 0] = (bf16)v.x; dst[i + 1] = (bf16)v.y;
        dst[i + 2] = (bf16)v.z; dst[i + 3] = (bf16)v.w;
    }
}

__global__ void cvt_wcat(const float* __restrict__ wq, const float* __restrict__ wk,
                         const float* __restrict__ wv, bf16* __restrict__ dst) {
    int i = (blockIdx.x * 256 + threadIdx.x) * 4;   // total 1536*1024
    const float* src; int off;
    if (i < 1024 * 1024)      { src = wq; off = i; }
    else if (i < 1280 * 1024) { src = wk; off = i - 1024 * 1024; }
    else                      { src = wv; off = i - 1280 * 1024; }
    float4 v = *(const float4*)(src + off);
    dst[i + 0] = (bf16)v.x; dst[i + 1] = (bf16)v.y;
    dst[i + 2] = (bf16)v.z; dst[i + 3] = (bf16)v.w;
}

// ---------------- RoPE cos/sin table: ctab[s][d] for d in 0..31 (period-32 in head dim) ----------------
__global__ void rope_tab_kernel(float2* __restrict__ ctab) {
    int i = blockIdx.x * 256 + threadIdx.x;   // 8192 = 256 x 32
    int s = i >> 5, d = i & 31;
    const float LN1 = 0.5756462732485115f;    // ln(10000)/16
    float pos = (d < 16) ? (float)(s >> 4) : (float)(s & 15);
    float ang = pos * expf(-(float)(d & 15) * LN1);
    float sn, cs; sincosf(ang, &sn, &cs);
    ctab[i] = make_float2(cs, sn);
}

// ================= BK=64 GEMM core (shared by both GEMMs) =================
// LDS tile 128x64 bf16 per matrix (16 KB), XOR-swizzled: row r, chunk c (16B)
// stored at slot r*8 + (c ^ (r&7)). Staged via 4 gl_lds16 calls/matrix.
// Per K-iter: 2 barriers, 8 gl_lds16, 16 ds_read_b128, 32 MFMA.
// Per-thread staging source (row, chunk) for call k: slot s = k*256 + tid.
#define GEMM_STAGE_PTRS(Mptr, tileRow, K, P)                                   \
    const bf16* P[4];                                                          \
    {                                                                          \
        _Pragma("unroll")                                                      \
        for (int k = 0; k < 4; k++) {                                          \
            int s = k * 256 + tid;                                             \
            int r = s >> 3, cp = s & 7;                                        \
            int c = cp ^ (r & 7);                                              \
            P[k] = (Mptr) + (size_t)((tileRow) + r) * (K) + c * 8;             \
        }                                                                      \
    }

__device__ __forceinline__ int swz(int row, int chunk) {   // LDS element offset
    return row * 64 + ((chunk ^ (row & 7)) * 8);
}

// ---------------- QKV GEMM with fused QKNorm + partial 2D-RoPE epilogue ----------------
// C[M,1536] = A[M,1024] @ W[1536,1024]^T. Each wave's 64 cols == one head.
// 1D grid, supertile swizzle: groups of 4 bm x 12 bn (bm fastest) -> ~4 MB hot set.
// NOTE: no min-waves launch_bounds — (256,6) capped VGPR at 40 and spilled the
// 64-VGPR accumulator to scratch (1 GB spill traffic, 4x regression, R4).
__global__ __launch_bounds__(256) void gemm_qkv(const bf16* __restrict__ A,
                                                const bf16* __restrict__ Bw,
                                                bf16* __restrict__ out,
                                                const float* __restrict__ qw,
                                                const float* __restrict__ kw,
                                                const float2* __restrict__ ctab) {
    __shared__ __align__(16) bf16 As[128 * 64];
    __shared__ __align__(16) bf16 Bs[128 * 64];
    const int tid  = threadIdx.x;
    const int wid  = tid >> 6, lane = tid & 63;
    const int quad = lane >> 4, r16 = lane & 15;
    const int bid = blockIdx.x;
    const int g = bid / 48, rr = bid - g * 48;
    const int bm = g * 4 + (rr & 3), bn = rr >> 2;
    const int wm = wid & 1, wn = wid >> 1;

    GEMM_STAGE_PTRS(A,  bm * 128, DIM, Ap)
    GEMM_STAGE_PTRS(Bw, bn * 128, DIM, Bp)

    f32x4 acc[4][4];
#pragma unroll
    for (int i = 0; i < 4; i++)
#pragma unroll
        for (int j = 0; j < 4; j++) acc[i][j] = (f32x4){0.f, 0.f, 0.f, 0.f};

    for (int k0 = 0; k0 < DIM; k0 += 64) {
        __syncthreads();
#pragma unroll
        for (int k = 0; k < 4; k++) {
            gl_lds16(Ap[k] + k0, As + (k * 256 + wid * 64) * 8);
            gl_lds16(Bp[k] + k0, Bs + (k * 256 + wid * 64) * 8);
        }
        __syncthreads();
#pragma unroll
        for (int ks = 0; ks < 2; ks++) {
            bf16x8 a[4], b[4];
#pragma unroll
            for (int i = 0; i < 4; i++) {
                a[i] = *(const bf16x8*)&As[swz(wm * 64 + i * 16 + r16, ks * 4 + quad)];
                b[i] = *(const bf16x8*)&Bs[swz(wn * 64 + i * 16 + r16, ks * 4 + quad)];
            }
#pragma unroll
            for (int i = 0; i < 4; i++)
#pragma unroll
                for (int j = 0; j < 4; j++)
                    acc[i][j] = __builtin_amdgcn_mfma_f32_16x16x32_bf16(a[i], b[j], acc[i][j], 0, 0, 0);
        }
    }

    const int colbase = bn * 128 + wn * 64;          // 64-aligned -> one head per wave
    const int rowbase = bm * 128 + wm * 64;
    if (bn < 10) {
        const float* w = (bn < 8) ? qw : kw;
        float wreg[4];
#pragma unroll
        for (int j = 0; j < 4; j++) wreg[j] = w[j * 16 + r16];
#pragma unroll
        for (int i = 0; i < 4; i++)
#pragma unroll
            for (int r = 0; r < 4; r++) {
                float ss = 0.f;
#pragma unroll
                for (int j = 0; j < 4; j++) ss += acc[i][j][r] * acc[i][j][r];
                ss += __shfl_xor(ss, 1, 64);
                ss += __shfl_xor(ss, 2, 64);
                ss += __shfl_xor(ss, 4, 64);
                ss += __shfl_xor(ss, 8, 64);
                float rms = rsqrtf(ss * (1.f / 64.f) + 1e-6f);
                float xv[4];
#pragma unroll
                for (int j = 0; j < 4; j++) xv[j] = acc[i][j][r] * rms * wreg[j];
                int gm = rowbase + i * 16 + quad * 4 + r;
                int s = gm % SLEN;
                if (s < NZ) {   // partial 2D RoPE; pairs (j, j+2) are lane-local
                    float2 cs0 = ctab[s * 32 + r16];
                    float2 cs1 = ctab[s * 32 + 16 + r16];
                    float a0 = xv[0] * cs0.x - xv[2] * cs0.y;
                    float a2 = xv[2] * cs0.x + xv[0] * cs0.y;
                    float a1 = xv[1] * cs1.x - xv[3] * cs1.y;
                    float a3 = xv[3] * cs1.x + xv[1] * cs1.y;
                    xv[0] = a0; xv[1] = a1; xv[2] = a2; xv[3] = a3;
                }
                size_t rowoff = (size_t)gm * NQKV + colbase + r16;
#pragma unroll
                for (int j = 0; j < 4; j++) out[rowoff + j * 16] = (bf16)xv[j];
            }
    } else {
#pragma unroll
        for (int i = 0; i < 4; i++)
#pragma unroll
            for (int j = 0; j < 4; j++)
#pragma unroll
                for (int r = 0; r < 4; r++) {
                    int gm = rowbase + i * 16 + quad * 4 + r;
                    int gn = colbase + j * 16 + r16;
                    out[(size_t)gm * NQKV + gn] = (bf16)acc[i][j][r];
                }
    }
}

// ---------------- O-projection GEMM: C[M,1024]=A@B^T, f32 out, BK=64 core ----------------
__global__ __launch_bounds__(256) void gemm_bt(const bf16* __restrict__ A,
                                               const bf16* __restrict__ Bw,
                                               float* __restrict__ Cout) {
    __shared__ __align__(16) bf16 As[128 * 64];
    __shared__ __align__(16) bf16 Bs[128 * 64];
    const int tid  = threadIdx.x;
    const int wid  = tid >> 6, lane = tid & 63;
    const int quad = lane >> 4, r16 = lane & 15;
    const int bid = blockIdx.x;
    const int g = bid / 32, rr = bid - g * 32;
    const int bm = g * 4 + (rr & 3), bn = rr >> 2;
    const int wm = wid & 1, wn = wid >> 1;

    GEMM_STAGE_PTRS(A,  bm * 128, DIM, Ap)
    GEMM_STAGE_PTRS(Bw, bn * 128, DIM, Bp)

    f32x4 acc[4][4];
#pragma unroll
    for (int i = 0; i < 4; i++)
#pragma unroll
        for (int j = 0; j < 4; j++) acc[i][j] = (f32x4){0.f, 0.f, 0.f, 0.f};

    for (int k0 = 0; k0 < DIM; k0 += 64) {
        __syncthreads();
#pragma unroll
        for (int k = 0; k < 4; k++) {
            gl_lds16(Ap[k] + k0, As + (k * 256 + wid * 64) * 8);
            gl_lds16(Bp[k] + k0, Bs + (k * 256 + wid * 64) * 8);
        }
        __syncthreads();
#pragma unroll
        for (int ks = 0; ks < 2; ks++) {
            bf16x8 a[4], b[4];
#pragma unroll
            for (int i = 0; i < 4; i++) {
                a[i] = *(const bf16x8*)&As[swz(wm * 64 + i * 16 + r16, ks * 4 + quad)];
                b[i] = *(const bf16x8*)&Bs[swz(wn * 64 + i * 16 + r16, ks * 4 + quad)];
            }
#pragma unroll
            for (int i = 0; i < 4; i++)
#pragma unroll
                for (int j = 0; j < 4; j++)
                    acc[i][j] = __builtin_amdgcn_mfma_f32_16x16x32_bf16(a[i], b[j], acc[i][j], 0, 0, 0);
        }
    }

#pragma unroll
    for (int i = 0; i < 4; i++)
#pragma unroll
        for (int j = 0; j < 4; j++)
#pragma unroll
            for (int r = 0; r < 4; r++) {
                int gm = bm * 128 + wm * 64 + i * 16 + quad * 4 + r;
                int gn = bn * 128 + wn * 64 + j * 16 + r16;
                Cout[(size_t)gm * DIM + gn] = acc[i][j][r];
            }
}

// ---------------- V transpose: qkv V region -> vt[(bt,kv)][d][key], zero-padded to 288 keys ----------------
__global__ __launch_bounds__(256) void vtrans_kernel(const bf16* __restrict__ qkv,
                                                     bf16* __restrict__ vt) {
    __shared__ bf16 Ls[64 * 272];
    const int tid = threadIdx.x;
    const int b = blockIdx.x, bt = b >> 2, kv = b & 3;
    const int part = tid >> 5;      // 0..7 (dim octet)
    const int rr   = tid & 31;      // row within pass
#pragma unroll
    for (int pass = 0; pass < 9; ++pass) {
        int row = pass * 32 + rr;
        if (row < SLEN) {
            bf16x8 v = *(const bf16x8*)(qkv + (size_t)(bt * SLEN + row) * NQKV + 1280 + kv * 64 + part * 8);
#pragma unroll
            for (int j = 0; j < 8; j++) Ls[(part * 8 + j) * 272 + row] = v[j];
        }
    }
    __syncthreads();
    const int d = tid >> 2, seg = tid & 3;
    size_t obase = ((size_t)b * 64 + d) * VPAD;
#pragma unroll
    for (int m = 0; m < 9; ++m) {
        int col = seg * 72 + m * 8;
        bf16x8 o;
#pragma unroll
        for (int j = 0; j < 8; j++) {
            int s = col + j;
            o[j] = (s < SLEN) ? Ls[d * 272 + s] : (bf16)0.f;
        }
        *(bf16x8*)(vt + obase + col) = o;
    }
}

// ---------------- attention v4: one wave per (32-row qtile-pair, head, bt) ----------------
// K prefetched one chunk ahead; softcap via odd-poly tanh (|z|<=0.16) + single exp2.
__global__ __launch_bounds__(256) void attn_kernel(const bf16* __restrict__ qkv,
                                                   const bf16* __restrict__ vt,
                                                   bf16* __restrict__ aout) {
    const int PLD = 40;
    __shared__ __align__(16) bf16 Pb[4][2][16 * PLD];   // per-wave, per-qtile P buffers

    const int tid = threadIdx.x;
    const int wid = tid >> 6, lane = tid & 63;
    const int quad = lane >> 4, r16 = lane & 15;
    const int qp = blockIdx.x;           // 0..8 (9 pairs of 16-row tiles = 288 rows)
    const int kv = blockIdx.y, bt = blockIdx.z;
    const int h = kv * 4 + wid;

    // Q A-fragments for two 16-row tiles
    bf16x8 qa[2][2];
#pragma unroll
    for (int qi = 0; qi < 2; qi++) {
        int q0 = qp * 32 + qi * 16 + r16;
        int qcl = q0 < SLEN ? q0 : SLEN - 1;
        const bf16* qb = qkv + (size_t)(bt * SLEN + qcl) * NQKV + h * HD + quad * 8;
        qa[qi][0] = *(const bf16x8*)qb;
        qa[qi][1] = *(const bf16x8*)(qb + 32);
    }

    f32x4 oacc[2][4];
    float lsum[2][4];
#pragma unroll
    for (int qi = 0; qi < 2; qi++)
#pragma unroll
        for (int i = 0; i < 4; i++) { oacc[qi][i] = (f32x4){0.f, 0.f, 0.f, 0.f}; lsum[qi][i] = 0.f; }

    const bf16* kbase = qkv + (size_t)bt * SLEN * NQKV + 1024 + kv * HD + quad * 8;
    const bf16* vbase = vt + (size_t)(bt * 4 + kv) * HD * VPAD;

    bf16x8 nk[2][2];
#pragma unroll
    for (int kt = 0; kt < 2; kt++) {
        int key = kt * 16 + r16;
        const bf16* kp = kbase + (size_t)key * NQKV;
        nk[kt][0] = *(const bf16x8*)kp;
        nk[kt][1] = *(const bf16x8*)(kp + 32);
    }

    for (int c = 0; c < 9; ++c) {
        bf16x8 ck[2][2];
#pragma unroll
        for (int kt = 0; kt < 2; kt++) { ck[kt][0] = nk[kt][0]; ck[kt][1] = nk[kt][1]; }
        if (c < 8) {   // prefetch next chunk's K
#pragma unroll
            for (int kt = 0; kt < 2; kt++) {
                int key = (c + 1) * 32 + kt * 16 + r16;
                int kc = key < SLEN ? key : SLEN - 1;
                const bf16* kp = kbase + (size_t)kc * NQKV;
                nk[kt][0] = *(const bf16x8*)kp;
                nk[kt][1] = *(const bf16x8*)(kp + 32);
            }
        }
        // V B-fragments (coalesced from vt; covered by QK+softcap latency)
        bf16x8 cv[4];
#pragma unroll
        for (int dt = 0; dt < 4; ++dt)
            cv[dt] = *(const bf16x8*)(vbase + (size_t)(dt * 16 + r16) * VPAD + c * 32 + quad * 8);

        // QK^T
        f32x4 s[2][2];
#pragma unroll
        for (int qi = 0; qi < 2; qi++)
#pragma unroll
            for (int kt = 0; kt < 2; kt++) {
                f32x4 t = (f32x4){0.f, 0.f, 0.f, 0.f};
                t = __builtin_amdgcn_mfma_f32_16x16x32_bf16(qa[qi][0], ck[kt][0], t, 0, 0, 0);
                t = __builtin_amdgcn_mfma_f32_16x16x32_bf16(qa[qi][1], ck[kt][1], t, 0, 0, 0);
                s[qi][kt] = t;
            }

        // softcap: p = exp(50*tanh(sc/400))  [|z|<=0.16 -> 5th-order odd poly, err<2e-7]
#pragma unroll
        for (int qi = 0; qi < 2; qi++) {
            bf16* Pw = &Pb[wid][qi][0];
#pragma unroll
            for (int kt = 0; kt < 2; kt++)
#pragma unroll
                for (int r = 0; r < 4; ++r) {
                    int key = c * 32 + kt * 16 + r16;
                    float sc = s[qi][kt][r];
                    float z = sc * 0.0025f;                       // sc*SCALE/50
                    float z2 = z * z;
                    float poly = fmaf(z2, fmaf(z2, 0.133333333f, -0.333333333f), 1.f);
                    float p = exp2f(sc * 0.18033688f * poly);     // 50*log2e*z*poly
                    p = (key < SLEN) ? p : 0.f;
                    bf16 pb = (bf16)p;
                    lsum[qi][r] += (float)pb;
                    Pw[(quad * 4 + r) * PLD + kt * 16 + r16] = pb;
                }
            // C-layout -> A-layout repack through per-wave LDS (wave-coherent, no barrier)
            bf16x8 pa = *(const bf16x8*)&Pw[r16 * PLD + quad * 8];
#pragma unroll
            for (int dt = 0; dt < 4; ++dt)
                oacc[qi][dt] = __builtin_amdgcn_mfma_f32_16x16x32_bf16(pa, cv[dt], oacc[qi][dt], 0, 0, 0);
        }
    }

    // finalize: reduce l across the 16 key-lanes, divide, store
#pragma unroll
    for (int qi = 0; qi < 2; qi++)
#pragma unroll
        for (int r = 0; r < 4; ++r) {
            float l = lsum[qi][r];
            l += __shfl_xor(l, 1, 64);
            l += __shfl_xor(l, 2, 64);
            l += __shfl_xor(l, 4, 64);
            l += __shfl_xor(l, 8, 64);
            float inv = 1.f / l;
            int q = qp * 32 + qi * 16 + quad * 4 + r;
            if (q < SLEN) {
                size_t base = (size_t)(bt * SLEN + q) * (NH * HD) + h * HD;
#pragma unroll
                for (int dt = 0; dt < 4; ++dt)
                    aout[base + dt * 16 + r16] = (bf16)(oacc[qi][dt][r] * inv);
            }
        }
}

// ---------------- launcher ----------------
extern "C" void kernel_launch(void* const* d_in, const int* in_sizes, int n_in,
                              void* d_out, int out_size, void* d_ws, size_t ws_size,
                              hipStream_t stream) {
    const float* x   = (const float*)d_in[0];
    const float* wq  = (const float*)d_in[1];
    const float* wk  = (const float*)d_in[2];
    const float* wv  = (const float*)d_in[3];
    const float* wo  = (const float*)d_in[4];
    const float* qnw = (const float*)d_in[5];
    const float* knw = (const float*)d_in[6];

    bf16* xbf  = (bf16*)d_ws;                        // 16896x1024 (reused as aout)
    bf16* wcat = xbf  + (size_t)MROWS * DIM;         // 1536x1024  [wq;wk;wv]
    bf16* wobf = wcat + (size_t)NQKV * DIM;          // 1024x1024
    bf16* qkv  = wobf + (size_t)DIM * DIM;           // 16896x1536
    bf16* vt   = qkv  + (size_t)MROWS * NQKV;        // 256x64x288
    float2* ctab = (float2*)(vt + (size_t)BTOT * NKV * HD * VPAD);  // 256x32
    bf16* aout = xbf;                                // xbf dead after gemm_qkv

    rope_tab_kernel<<<32, 256, 0, stream>>>(ctab);
    cvt_f32_bf16<<<(MROWS * DIM) / 1024, 256, 0, stream>>>(x, xbf, MROWS * DIM);
    cvt_wcat<<<(NQKV * DIM) / 1024, 256, 0, stream>>>(wq, wk, wv, wcat);
    cvt_f32_bf16<<<(DIM * DIM) / 1024, 256, 0, stream>>>(wo, wobf, DIM * DIM);

    gemm_qkv<<<(MROWS / 128) * (NQKV / 128), 256, 0, stream>>>(xbf, wcat, qkv, qnw, knw, ctab);
    vtrans_kernel<<<BTOT * NKV, 256, 0, stream>>>(qkv, vt);
    attn_kernel<<<dim3(9, NKV, BTOT), 256, 0, stream>>>(qkv, vt, aout);
    gemm_bt<<<(MROWS / 128) * (DIM / 128), 256, 0, stream>>>(aout, wobf, (float*)d_out);
}